// Round 4
// baseline (176.650 us; speedup 1.0000x reference)
//
#include <hip/hip_runtime.h>
#include <math.h>
#include <stdint.h>

#define NEXP 48
#define NCAT 30
#define SP_TOT 13440            // 24*28*20
#define M_TOT (NCAT * SP_TOT)   // 403200

// One thread per voxel-column. Algorithm: find tau = K-th largest |g| via an
// in-register bitonic sort (compile-time network => pure v_min/v_max chain),
// then masked FMA with shape_experts. Exactness: a count check detects any
// |value| tie at the selection boundary (and non-24 K) and falls back to an
// exact stable-ranked path (u64 keys == jax.lax.top_k semantics).
__global__ __launch_bounds__(256) void moe_topk_contract(
    const float* __restrict__ gm, const float* __restrict__ gf,
    const float* __restrict__ se, const int* __restrict__ kptr,
    float* __restrict__ out)
{
    const int m = blockIdx.x * 256 + threadIdx.x;   // column id (c,x,y,z flat)
    const int K = *kptr;

    #pragma unroll 1
    for (int t = 0; t < 2; ++t) {
        const float* __restrict__ g_ = t ? gf : gm;

        float g[NEXP];
        #pragma unroll
        for (int k = 0; k < NEXP; ++k) g[k] = g_[k * M_TOT + m];

        float acc = 0.f;
        bool done = false;

        if (K == 24) {
            // ---- bitonic sort (ascending) of |g| padded to 64 with -inf ----
            float s[64];
            #pragma unroll
            for (int k = 0; k < NEXP; ++k) s[k] = fabsf(g[k]);
            #pragma unroll
            for (int k = NEXP; k < 64; ++k) s[k] = -INFINITY;

            #pragma unroll
            for (int kk = 2; kk <= 64; kk <<= 1) {
                #pragma unroll
                for (int j = kk >> 1; j > 0; j >>= 1) {
                    #pragma unroll
                    for (int i = 0; i < 64; ++i) {
                        const int l = i ^ j;
                        if (l > i) {
                            const float lo = fminf(s[i], s[l]);
                            const float hi = fmaxf(s[i], s[l]);
                            if ((i & kk) == 0) { s[i] = lo; s[l] = hi; }
                            else               { s[i] = hi; s[l] = lo; }
                        }
                    }
                }
            }
            const float tau = s[40];   // 24th largest of 64 (pads are -inf)

            // ---- boundary-tie detection ----
            int cgt = 0, cge = 0;
            #pragma unroll
            for (int k = 0; k < NEXP; ++k) {
                cgt += (fabsf(g[k]) >  tau) ? 1 : 0;
                cge += (fabsf(g[k]) >= tau) ? 1 : 0;
            }
            if (cgt == 23 && cge == 24) {
                #pragma unroll
                for (int k = 0; k < NEXP; ++k) {
                    const float sv = se[k * M_TOT + m];
                    acc = (fabsf(g[k]) >= tau) ? fmaf(g[k], sv, acc) : acc;
                }
                done = true;
            }
        }

        if (!done) {
            // exact generic path (rare / non-24 K): stable ranks via u64 keys,
            // fully rolled, operands re-read from global (L2/L3-hot).
            acc = 0.f;
            #pragma unroll 1
            for (int i2 = 0; i2 < NEXP; ++i2) {
                const float gi = g_[i2 * M_TOT + m];
                const uint64_t ki =
                    ((uint64_t)(__float_as_uint(gi) & 0x7fffffffu) << 32)
                    | (uint32_t)(NEXP - 1 - i2);
                int r = 0;
                #pragma unroll 1
                for (int j2 = 0; j2 < NEXP; ++j2) {
                    const float gj = g_[j2 * M_TOT + m];
                    const uint64_t kj =
                        ((uint64_t)(__float_as_uint(gj) & 0x7fffffffu) << 32)
                        | (uint32_t)(NEXP - 1 - j2);
                    r += (kj > ki) ? 1 : 0;
                }
                if (r < K) acc = fmaf(gi, se[i2 * M_TOT + m], acc);
            }
        }

        out[t * M_TOT + m] = acc;
    }
}

// Kernel 2: in-place softmax over the category dim (stride SP_TOT).
__global__ __launch_bounds__(256) void softmax_c(float* __restrict__ out)
{
    const int q = blockIdx.x * blockDim.x + threadIdx.x;
    if (q >= 2 * SP_TOT) return;
    const int t  = q / SP_TOT;
    const int sp = q - t * SP_TOT;
    float* __restrict__ base = out + t * M_TOT + sp;

    float v[NCAT];
    float mx = -INFINITY;
    #pragma unroll
    for (int c = 0; c < NCAT; ++c) {
        v[c] = base[c * SP_TOT];
        mx = fmaxf(mx, v[c]);
    }
    float sum = 0.f;
    #pragma unroll
    for (int c = 0; c < NCAT; ++c) {
        v[c] = __expf(v[c] - mx);
        sum += v[c];
    }
    const float inv = 1.f / sum;
    #pragma unroll
    for (int c = 0; c < NCAT; ++c)
        base[c * SP_TOT] = v[c] * inv;
}

extern "C" void kernel_launch(void* const* d_in, const int* in_sizes, int n_in,
                              void* d_out, int out_size, void* d_ws, size_t ws_size,
                              hipStream_t stream) {
    const float* gm   = (const float*)d_in[0];
    const float* gf   = (const float*)d_in[1];
    const float* se   = (const float*)d_in[2];
    const int*   kptr = (const int*)d_in[3];
    float* out = (float*)d_out;

    const int grid1 = M_TOT / 256;                 // 1575
    moe_topk_contract<<<grid1, 256, 0, stream>>>(gm, gf, se, kptr, out);

    const int grid2 = (2 * SP_TOT + 255) / 256;    // 105
    softmax_c<<<grid2, 256, 0, stream>>>(out);
}